// Round 3
// baseline (18167.685 us; speedup 1.0000x reference)
//
#include <hip/hip_runtime.h>

// Decoder: B=16, T=128, V=32000, E=512, H=1024 (2 LSTM layers), CTX=2048.
// dec_seq: persistent kernel, 256 blocks x 512 threads.
//   Grid barrier = per-block arrival flag (own cacheline, release STORE) +
//   block-0 wave-0 parallel poll + one generation word. No same-line RMW chain
//   (previous fetch_add barrier serialized 256 cross-XCD atomics = ~50us/step).
// fc_gemm: fp32 tiled GEMM [2048x1024]x[32000x1024]^T -> [16][128][32000].

#define NBLK 256

__device__ __forceinline__ float sigf(float x) { return 1.0f / (1.0f + __expf(-x)); }
__device__ __forceinline__ float tanh_(float x) {
  x = fminf(15.0f, fmaxf(-15.0f, x));
  float e = __expf(2.0f * x);
  return (e - 1.0f) / (e + 1.0f);
}

// bar layout (uint32 indices): [0] = generation word; [16 + wgid*16] = per-block
// arrival flag (64B stride). Monotonic step counter, memset to 0 per launch.
__device__ __forceinline__ void gsync(unsigned step, unsigned* bar) {
  __threadfence();
  __syncthreads();
  const int tid = threadIdx.x;
  if (blockIdx.x == 0) {
    if (tid < 64) {
      if (tid == 0)
        __hip_atomic_store(bar + 16, step, __ATOMIC_RELEASE, __HIP_MEMORY_SCOPE_AGENT);
      const int base = 16 + tid * 64;  // 4 flags per lane: +0,+16,+32,+48
      for (;;) {
        bool mine = true;
#pragma unroll
        for (int j = 0; j < 4; ++j)
          mine &= (__hip_atomic_load(bar + base + j * 16, __ATOMIC_ACQUIRE,
                                     __HIP_MEMORY_SCOPE_AGENT) >= step);
        if (__all(mine)) break;
        __builtin_amdgcn_s_sleep(1);
      }
      if (tid == 0)
        __hip_atomic_store(bar, step, __ATOMIC_RELEASE, __HIP_MEMORY_SCOPE_AGENT);
    }
  } else {
    if (tid == 0) {
      __hip_atomic_store(bar + 16 + blockIdx.x * 16, step, __ATOMIC_RELEASE,
                         __HIP_MEMORY_SCOPE_AGENT);
      while (__hip_atomic_load(bar, __ATOMIC_ACQUIRE, __HIP_MEMORY_SCOPE_AGENT) < step)
        __builtin_amdgcn_s_sleep(1);
    }
  }
  __syncthreads();
}

// NOTE: function, not macro — macro params named w/x collide with .w/.x members.
__device__ __forceinline__ void dot4(float& a, float4 wv, float4 xv) {
  a = fmaf(wv.x, xv.x, a);
  a = fmaf(wv.y, xv.y, a);
  a = fmaf(wv.z, xv.z, a);
  a = fmaf(wv.w, xv.w, a);
}

#define DECL_ACC                                                        \
  float acc00 = 0.f, acc01 = 0.f, acc02 = 0.f, acc03 = 0.f,             \
        acc10 = 0.f, acc11 = 0.f, acc12 = 0.f, acc13 = 0.f,             \
        acc20 = 0.f, acc21 = 0.f, acc22 = 0.f, acc23 = 0.f,             \
        acc30 = 0.f, acc31 = 0.f, acc32 = 0.f, acc33 = 0.f;

#define KSTEP(p0, p1, p2, p3, K4)                                       \
  {                                                                     \
    const float4 xv0 = *(const float4*)&xls[bq4][(K4)];                 \
    const float4 xv1 = *(const float4*)&xls[bq4 + 1][(K4)];             \
    const float4 xv2 = *(const float4*)&xls[bq4 + 2][(K4)];             \
    const float4 xv3 = *(const float4*)&xls[bq4 + 3][(K4)];             \
    float4 wv;                                                          \
    wv = *(const float4*)(p0);                                          \
    dot4(acc00, wv, xv0); dot4(acc01, wv, xv1);                         \
    dot4(acc02, wv, xv2); dot4(acc03, wv, xv3);                         \
    wv = *(const float4*)(p1);                                          \
    dot4(acc10, wv, xv0); dot4(acc11, wv, xv1);                         \
    dot4(acc12, wv, xv2); dot4(acc13, wv, xv3);                         \
    wv = *(const float4*)(p2);                                          \
    dot4(acc20, wv, xv0); dot4(acc21, wv, xv1);                         \
    dot4(acc22, wv, xv2); dot4(acc23, wv, xv3);                         \
    wv = *(const float4*)(p3);                                          \
    dot4(acc30, wv, xv0); dot4(acc31, wv, xv1);                         \
    dot4(acc32, wv, xv2); dot4(acc33, wv, xv3);                         \
  }

#define RED5(v)                \
  {                            \
    v += __shfl_xor(v, 1);     \
    v += __shfl_xor(v, 2);     \
    v += __shfl_xor(v, 4);     \
    v += __shfl_xor(v, 8);     \
    v += __shfl_xor(v, 16);    \
  }

#define REDUCE_ALL                                                     \
  {                                                                    \
    RED5(acc00) RED5(acc01) RED5(acc02) RED5(acc03)                    \
    RED5(acc10) RED5(acc11) RED5(acc12) RED5(acc13)                    \
    RED5(acc20) RED5(acc21) RED5(acc22) RED5(acc23)                    \
    RED5(acc30) RED5(acc31) RED5(acc32) RED5(acc33)                    \
  }

#define WRITE_GLS                                                                   \
  {                                                                                 \
    if (kc == 0) {                                                                  \
      gls[jq][0][bq4] = acc00; gls[jq][0][bq4 + 1] = acc01;                         \
      gls[jq][0][bq4 + 2] = acc02; gls[jq][0][bq4 + 3] = acc03;                     \
      gls[jq][1][bq4] = acc10; gls[jq][1][bq4 + 1] = acc11;                         \
      gls[jq][1][bq4 + 2] = acc12; gls[jq][1][bq4 + 3] = acc13;                     \
      gls[jq][2][bq4] = acc20; gls[jq][2][bq4 + 1] = acc21;                         \
      gls[jq][2][bq4 + 2] = acc22; gls[jq][2][bq4 + 3] = acc23;                     \
      gls[jq][3][bq4] = acc30; gls[jq][3][bq4 + 1] = acc31;                         \
      gls[jq][3][bq4 + 2] = acc32; gls[jq][3][bq4 + 3] = acc33;                     \
    }                                                                               \
  }

__global__ __launch_bounds__(512, 2) void dec_seq(
    const float* __restrict__ enc_h, const float* __restrict__ enc_c,
    const int* __restrict__ tgt, const float* __restrict__ emb,
    const float* __restrict__ wih0, const float* __restrict__ whh0,
    const float* __restrict__ bih0, const float* __restrict__ bhh0,
    const float* __restrict__ wih1, const float* __restrict__ whh1,
    const float* __restrict__ bih1, const float* __restrict__ bhh1,
    float* __restrict__ h0b, float* __restrict__ h1b,
    float* __restrict__ x1, float* __restrict__ out2,
    unsigned* bar) {
  __shared__ float xls[16][2052];   // [batch][k], padded rows (2052 % 32 == 4)
  __shared__ float gls[4][4][16];   // [gate][dj][b]

  const int tid = threadIdx.x;
  const int wgid = blockIdx.x;          // 0..255 -> 4 hidden units each
  const int kc = tid & 31;              // split-K lane
  const int combo = tid >> 5;           // 0..15
  const int jq = combo >> 2;            // gate 0..3 (i,f,g,o)
  const int bq4 = (combo & 3) * 4;      // batch quad
  const int w4 = wgid * 4;
  unsigned step = 0;                    // monotonic barrier generation

  const int j0 = jq * 1024 + w4;        // first of this thread's 4 gate rows
  const float* wih0r0 = wih0 + (size_t)(j0 + 0) * 2560;
  const float* wih0r1 = wih0 + (size_t)(j0 + 1) * 2560;
  const float* wih0r2 = wih0 + (size_t)(j0 + 2) * 2560;
  const float* wih0r3 = wih0 + (size_t)(j0 + 3) * 2560;
  const float* whh0r0 = whh0 + (size_t)(j0 + 0) * 1024;
  const float* whh0r1 = whh0 + (size_t)(j0 + 1) * 1024;
  const float* whh0r2 = whh0 + (size_t)(j0 + 2) * 1024;
  const float* whh0r3 = whh0 + (size_t)(j0 + 3) * 1024;
  const float* wih1r0 = wih1 + (size_t)(j0 + 0) * 1024;
  const float* wih1r1 = wih1 + (size_t)(j0 + 1) * 1024;
  const float* wih1r2 = wih1 + (size_t)(j0 + 2) * 1024;
  const float* wih1r3 = wih1 + (size_t)(j0 + 3) * 1024;
  const float* whh1r0 = whh1 + (size_t)(j0 + 0) * 1024;
  const float* whh1r1 = whh1 + (size_t)(j0 + 1) * 1024;
  const float* whh1r2 = whh1 + (size_t)(j0 + 2) * 1024;
  const float* whh1r3 = whh1 + (size_t)(j0 + 3) * 1024;

  // gate-thread persistent state (valid for tid < 64)
  const int gdj = tid >> 4;  // 0..3
  const int gb = tid & 15;   // batch
  float cpA0 = 0.f, cpA1 = 0.f, cpA2 = 0.f, cpA3 = 0.f;
  float cpB0 = 0.f, cpB1 = 0.f, cpB2 = 0.f, cpB3 = 0.f;
  float c0r = 0.f, c1r = 0.f;

  // ---------------- INIT: ctx projection + biases + h/c init ----------------
  // stage ctx[b][k] = enc_h[k>>9][b][k&511] into xls[b][0..2047]
#pragma unroll
  for (int c = 0; c < 16; ++c) {
    int f4 = tid + c * 512;
    int b = f4 >> 9, kq = f4 & 511;
    const float4 v = *(const float4*)(enc_h + (kq >> 7) * 8192 + b * 512 + (kq & 127) * 4);
    *(float4*)&xls[b][kq * 4] = v;
  }
  __syncthreads();
  {
    DECL_ACC
#pragma unroll 4
    for (int i = 0; i < 16; ++i) {
      const int k4 = i * 128 + kc * 4;
      KSTEP(wih0r0 + 512 + k4, wih0r1 + 512 + k4, wih0r2 + 512 + k4, wih0r3 + 512 + k4, k4)
    }
    REDUCE_ALL
    WRITE_GLS
  }
  __syncthreads();
  if (tid < 64) {
    const int jp = w4 + gdj;
    cpA0 = gls[0][gdj][gb] + bih0[jp] + bhh0[jp];
    cpA1 = gls[1][gdj][gb] + bih0[1024 + jp] + bhh0[1024 + jp];
    cpA2 = gls[2][gdj][gb] + bih0[2048 + jp] + bhh0[2048 + jp];
    cpA3 = gls[3][gdj][gb] + bih0[3072 + jp] + bhh0[3072 + jp];
    cpB0 = bih1[jp] + bhh1[jp];
    cpB1 = bih1[1024 + jp] + bhh1[1024 + jp];
    cpB2 = bih1[2048 + jp] + bhh1[2048 + jp];
    cpB3 = bih1[3072 + jp] + bhh1[3072 + jp];
    const int dir = jp >> 9, e = jp & 511;
    c0r = enc_c[dir * 8192 + gb * 512 + e];
    c1r = enc_c[(2 + dir) * 8192 + gb * 512 + e];
    h0b[gb * 1024 + jp] = enc_h[dir * 8192 + gb * 512 + e];
    h1b[gb * 1024 + jp] = enc_h[(2 + dir) * 8192 + gb * 512 + e];
  }
  gsync(++step, bar);

  // ---------------- LAYER 0: 128 steps, K = 512 (emb) + 1024 (h) ----------------
  int cur = 0;
  for (int t = 0; t < 128; ++t) {
#pragma unroll
    for (int c = 0; c < 4; ++c) {
      int f4 = tid + c * 512;
      int b = f4 >> 7, kq = f4 & 127;
      int tok = (t == 0) ? 1 : tgt[b * 128 + (t - 1)];
      const float4 v = *(const float4*)(emb + (size_t)tok * 512 + kq * 4);
      *(float4*)&xls[b][kq * 4] = v;
    }
    const float* hs = h0b + cur * 16384;
#pragma unroll
    for (int c = 0; c < 8; ++c) {
      int f4 = tid + c * 512;
      int b = f4 >> 8, kq = f4 & 255;
      *(float4*)&xls[b][512 + kq * 4] = *(const float4*)(hs + b * 1024 + kq * 4);
    }
    __syncthreads();
    {
      DECL_ACC
#pragma unroll 4
      for (int i = 0; i < 4; ++i) {
        const int k4 = i * 128 + kc * 4;
        KSTEP(wih0r0 + k4, wih0r1 + k4, wih0r2 + k4, wih0r3 + k4, k4)
      }
#pragma unroll 4
      for (int i = 4; i < 12; ++i) {
        const int k4 = i * 128 + kc * 4;
        const int kh = k4 - 512;
        KSTEP(whh0r0 + kh, whh0r1 + kh, whh0r2 + kh, whh0r3 + kh, k4)
      }
      REDUCE_ALL
      WRITE_GLS
    }
    __syncthreads();
    if (tid < 64) {
      const int jp = w4 + gdj;
      float gi = gls[0][gdj][gb] + cpA0;
      float gf = gls[1][gdj][gb] + cpA1;
      float gg = gls[2][gdj][gb] + cpA2;
      float go = gls[3][gdj][gb] + cpA3;
      c0r = sigf(gf) * c0r + sigf(gi) * tanh_(gg);
      float h = sigf(go) * tanh_(c0r);
      h0b[(cur ^ 1) * 16384 + gb * 1024 + jp] = h;
      x1[t * 16384 + gb * 1024 + jp] = h;
    }
    gsync(++step, bar);
    cur ^= 1;
  }

  // ---------------- LAYER 1: 128 steps, K = 1024 (x1) + 1024 (h) ----------------
  int cur2 = 0;
  for (int t = 0; t < 128; ++t) {
    const float* xs = x1 + t * 16384;
#pragma unroll
    for (int c = 0; c < 8; ++c) {
      int f4 = tid + c * 512;
      int b = f4 >> 8, kq = f4 & 255;
      *(float4*)&xls[b][kq * 4] = *(const float4*)(xs + b * 1024 + kq * 4);
    }
    const float* hs = h1b + cur2 * 16384;
#pragma unroll
    for (int c = 0; c < 8; ++c) {
      int f4 = tid + c * 512;
      int b = f4 >> 8, kq = f4 & 255;
      *(float4*)&xls[b][1024 + kq * 4] = *(const float4*)(hs + b * 1024 + kq * 4);
    }
    __syncthreads();
    {
      DECL_ACC
#pragma unroll 4
      for (int i = 0; i < 8; ++i) {
        const int k4 = i * 128 + kc * 4;
        KSTEP(wih1r0 + k4, wih1r1 + k4, wih1r2 + k4, wih1r3 + k4, k4)
      }
#pragma unroll 4
      for (int i = 8; i < 16; ++i) {
        const int k4 = i * 128 + kc * 4;
        const int kh = k4 - 1024;
        KSTEP(whh1r0 + kh, whh1r1 + kh, whh1r2 + kh, whh1r3 + kh, k4)
      }
      REDUCE_ALL
      WRITE_GLS
    }
    __syncthreads();
    if (tid < 64) {
      const int jp = w4 + gdj;
      float gi = gls[0][gdj][gb] + cpB0;
      float gf = gls[1][gdj][gb] + cpB1;
      float gg = gls[2][gdj][gb] + cpB2;
      float go = gls[3][gdj][gb] + cpB3;
      c1r = sigf(gf) * c1r + sigf(gi) * tanh_(gg);
      float h = sigf(go) * tanh_(c1r);
      h1b[(cur2 ^ 1) * 16384 + gb * 1024 + jp] = h;
      out2[(t * 16 + gb) * 1024 + jp] = tanh_(h);
    }
    gsync(++step, bar);
    cur2 ^= 1;
  }
}

// logits[b][t][v] = sum_h out2[t*16+b][h] * fcw[v][h] + fcb[v]
__global__ __launch_bounds__(256, 2) void fc_gemm(
    const float* __restrict__ A, const float* __restrict__ Bw,
    const float* __restrict__ bias, float* __restrict__ C) {
  __shared__ float Asl[32][128];  // [k][m]
  __shared__ float Bsl[32][128];  // [k][n]
  const int tid = threadIdx.x;
  const int m0 = blockIdx.x * 128;  // 16 m-tiles (fast axis -> L2 reuse of Bw)
  const int n0 = blockIdx.y * 128;  // 250 n-tiles
  const int q = tid >> 6;
  const int tx = ((q & 1) << 3) + (tid & 7);
  const int ty = ((q >> 1) << 3) + ((tid >> 3) & 7);
  const int sm = tid >> 1;
  const int sh = (tid & 1) << 4;
  float acc[8][8] = {};
  const float* As = A + (size_t)(m0 + sm) * 1024 + sh;
  const float* Bs = Bw + (size_t)(n0 + sm) * 1024 + sh;

  for (int k0 = 0; k0 < 1024; k0 += 32) {
    float4 a0 = *(const float4*)(As + k0);
    float4 a1 = *(const float4*)(As + k0 + 4);
    float4 a2 = *(const float4*)(As + k0 + 8);
    float4 a3 = *(const float4*)(As + k0 + 12);
    float4 b0 = *(const float4*)(Bs + k0);
    float4 b1 = *(const float4*)(Bs + k0 + 4);
    float4 b2 = *(const float4*)(Bs + k0 + 8);
    float4 b3 = *(const float4*)(Bs + k0 + 12);
    float ta[16], tb[16];
    *(float4*)&ta[0] = a0; *(float4*)&ta[4] = a1; *(float4*)&ta[8] = a2; *(float4*)&ta[12] = a3;
    *(float4*)&tb[0] = b0; *(float4*)&tb[4] = b1; *(float4*)&tb[8] = b2; *(float4*)&tb[12] = b3;
#pragma unroll
    for (int u = 0; u < 16; ++u) {
      Asl[sh + u][sm] = ta[u];
      Bsl[sh + u][sm] = tb[u];
    }
    __syncthreads();
#pragma unroll 8
    for (int kk = 0; kk < 32; ++kk) {
      const float4 A0 = *(const float4*)&Asl[kk][ty * 8];
      const float4 A1 = *(const float4*)&Asl[kk][ty * 8 + 4];
      const float4 B0 = *(const float4*)&Bsl[kk][tx * 8];
      const float4 B1 = *(const float4*)&Bsl[kk][tx * 8 + 4];
      const float av[8] = {A0.x, A0.y, A0.z, A0.w, A1.x, A1.y, A1.z, A1.w};
      const float bv[8] = {B0.x, B0.y, B0.z, B0.w, B1.x, B1.y, B1.z, B1.w};
#pragma unroll
      for (int i = 0; i < 8; ++i)
#pragma unroll
        for (int j = 0; j < 8; ++j) acc[i][j] = fmaf(av[i], bv[j], acc[i][j]);
    }
    __syncthreads();
  }

  const float4 bb0 = *(const float4*)&bias[n0 + tx * 8];
  const float4 bb1 = *(const float4*)&bias[n0 + tx * 8 + 4];
  const float bv[8] = {bb0.x, bb0.y, bb0.z, bb0.w, bb1.x, bb1.y, bb1.z, bb1.w};
#pragma unroll
  for (int i = 0; i < 8; ++i) {
    const int m = m0 + ty * 8 + i;
    float* dst = C + ((size_t)(m & 15) * 128 + (m >> 4)) * 32000 + n0 + tx * 8;
    float4 o0, o1;
    o0.x = acc[i][0] + bv[0]; o0.y = acc[i][1] + bv[1];
    o0.z = acc[i][2] + bv[2]; o0.w = acc[i][3] + bv[3];
    o1.x = acc[i][4] + bv[4]; o1.y = acc[i][5] + bv[5];
    o1.z = acc[i][6] + bv[6]; o1.w = acc[i][7] + bv[7];
    *(float4*)dst = o0;
    *(float4*)(dst + 4) = o1;
  }
}

extern "C" void kernel_launch(void* const* d_in, const int* in_sizes, int n_in,
                              void* d_out, int out_size, void* d_ws, size_t ws_size,
                              hipStream_t stream) {
  const float* enc_h = (const float*)d_in[0];
  const float* enc_c = (const float*)d_in[1];
  const int* tgt = (const int*)d_in[2];
  const float* emb = (const float*)d_in[3];
  const float* wih0 = (const float*)d_in[4];
  const float* whh0 = (const float*)d_in[5];
  const float* bih0 = (const float*)d_in[6];
  const float* bhh0 = (const float*)d_in[7];
  const float* wih1 = (const float*)d_in[8];
  const float* whh1 = (const float*)d_in[9];
  const float* bih1 = (const float*)d_in[10];
  const float* bhh1 = (const float*)d_in[11];
  const float* fcw = (const float*)d_in[12];
  const float* fcb = (const float*)d_in[13];
  float* logits = (float*)d_out;

  unsigned* bar = (unsigned*)d_ws;                  // 32 KB barrier region
  float* wsf = (float*)((char*)d_ws + 32768);
  float* h0b = wsf;                   // 2 * 16384
  float* h1b = wsf + 32768;           // 2 * 16384
  float* x1 = wsf + 65536;            // 128 * 16384
  float* out2 = x1 + 2097152;         // 128 * 16384

  // zero generation word + 256 arrival flags (64B stride) each launch
  hipMemsetAsync(d_ws, 0, 64 + 256 * 64, stream);
  dec_seq<<<NBLK, 512, 0, stream>>>(enc_h, enc_c, tgt, emb, wih0, whh0, bih0, bhh0,
                                    wih1, whh1, bih1, bhh1, h0b, h1b, x1, out2, bar);
  fc_gemm<<<dim3(16, 250), 256, 0, stream>>>(out2, fcw, fcb, logits);
}

// Round 4
// 4688.602 us; speedup vs baseline: 3.8749x; 3.8749x over previous
//
#include <hip/hip_runtime.h>

// Decoder: B=16, T=128, V=32000, E=512, H=1024 (2 LSTM layers), CTX=2048.
// dec_seq: persistent kernel, 256 blocks x 512 threads.
//   Grid sync: relaxed-poll flag barrier (NO acquire loads in spin loops --
//   agent-scope acquire emits buffer_inv per poll, which flushed L2 every
//   ~30ns and forced 25-33MB/step of weight refetch; that was the 60us/step).
//   Cross-block data (h0b/h1b/x1) moves via explicit sc0 sc1 bypass
//   loads/stores (write-through / L2-bypass), so no cache maintenance is
//   needed and weights stay hot in L2/L3.
// fc_gemm: fp32 tiled GEMM [2048x1024]x[32000x1024]^T -> [16][128][32000].

#define NBLK 256

typedef float f32x4 __attribute__((ext_vector_type(4)));

__device__ __forceinline__ float sigf(float x) { return 1.0f / (1.0f + __expf(-x)); }
__device__ __forceinline__ float tanh_(float x) {
  x = fminf(15.0f, fmaxf(-15.0f, x));
  float e = __expf(2.0f * x);
  return (e - 1.0f) / (e + 1.0f);
}

// Coherent (L2-bypass) scalar store: write-through to memory side.
__device__ __forceinline__ void st_cv(float* p, float v) {
  asm volatile("global_store_dword %0, %1, off sc0 sc1" :: "v"(p), "v"(v) : "memory");
}

// 8 coherent dwordx4 loads in flight, one waitcnt.
__device__ __forceinline__ void ld8_cv(const float* a0, const float* a1, const float* a2,
                                       const float* a3, const float* a4, const float* a5,
                                       const float* a6, const float* a7,
                                       f32x4& v0, f32x4& v1, f32x4& v2, f32x4& v3,
                                       f32x4& v4, f32x4& v5, f32x4& v6, f32x4& v7) {
  asm volatile(
      "global_load_dwordx4 %0, %8, off sc0 sc1\n\t"
      "global_load_dwordx4 %1, %9, off sc0 sc1\n\t"
      "global_load_dwordx4 %2, %10, off sc0 sc1\n\t"
      "global_load_dwordx4 %3, %11, off sc0 sc1\n\t"
      "global_load_dwordx4 %4, %12, off sc0 sc1\n\t"
      "global_load_dwordx4 %5, %13, off sc0 sc1\n\t"
      "global_load_dwordx4 %6, %14, off sc0 sc1\n\t"
      "global_load_dwordx4 %7, %15, off sc0 sc1\n\t"
      "s_waitcnt vmcnt(0)"
      : "=&v"(v0), "=&v"(v1), "=&v"(v2), "=&v"(v3),
        "=&v"(v4), "=&v"(v5), "=&v"(v6), "=&v"(v7)
      : "v"(a0), "v"(a1), "v"(a2), "v"(a3), "v"(a4), "v"(a5), "v"(a6), "v"(a7)
      : "memory");
}

// Stage a 16x1024 float slab (64KB) src -> xls[0..15][dstoff..dstoff+1023].
// Thread layout: float index = 4*tid + 2048*c, c=0..7.
__device__ __forceinline__ void stage64k(const float* src, int dstoff, int tid,
                                         float xls[16][2052]) {
  f32x4 v0, v1, v2, v3, v4, v5, v6, v7;
  const float* s = src + 4 * tid;
  ld8_cv(s, s + 2048, s + 4096, s + 6144, s + 8192, s + 10240, s + 12288, s + 14336,
         v0, v1, v2, v3, v4, v5, v6, v7);
  const int bb = tid >> 8, k4 = (tid & 255) * 4;
  *(f32x4*)&xls[bb + 0][dstoff + k4] = v0;
  *(f32x4*)&xls[bb + 2][dstoff + k4] = v1;
  *(f32x4*)&xls[bb + 4][dstoff + k4] = v2;
  *(f32x4*)&xls[bb + 6][dstoff + k4] = v3;
  *(f32x4*)&xls[bb + 8][dstoff + k4] = v4;
  *(f32x4*)&xls[bb + 10][dstoff + k4] = v5;
  *(f32x4*)&xls[bb + 12][dstoff + k4] = v6;
  *(f32x4*)&xls[bb + 14][dstoff + k4] = v7;
}

// bar layout (uint32 idx): [0] = generation word; [16 + wgid*16] = per-block
// arrival flag (64B stride). Monotonic step counter, memset 0 per launch.
// All polls RELAXED (no buffer_inv); flag stores RELEASE (orders wave-0's
// bypass data stores; explicit vmcnt(0) as belt-and-suspenders).
__device__ __forceinline__ void gsync(unsigned step, unsigned* bar) {
  __syncthreads();
  const int tid = threadIdx.x;
  if (blockIdx.x == 0) {
    if (tid < 64) {
      if (tid == 0) {
        asm volatile("s_waitcnt vmcnt(0)" ::: "memory");
        __hip_atomic_store(bar + 16, step, __ATOMIC_RELEASE, __HIP_MEMORY_SCOPE_AGENT);
      }
      const int base = 16 + tid * 64;  // 4 flags per lane: +0,+16,+32,+48
      for (;;) {
        bool mine = true;
#pragma unroll
        for (int j = 0; j < 4; ++j)
          mine &= (__hip_atomic_load(bar + base + j * 16, __ATOMIC_RELAXED,
                                     __HIP_MEMORY_SCOPE_AGENT) >= step);
        if (__all(mine)) break;
        __builtin_amdgcn_s_sleep(1);
      }
      asm volatile("" ::: "memory");
      if (tid == 0)
        __hip_atomic_store(bar, step, __ATOMIC_RELEASE, __HIP_MEMORY_SCOPE_AGENT);
    }
  } else {
    if (tid == 0) {
      asm volatile("s_waitcnt vmcnt(0)" ::: "memory");
      __hip_atomic_store(bar + 16 + blockIdx.x * 16, step, __ATOMIC_RELEASE,
                         __HIP_MEMORY_SCOPE_AGENT);
      while (__hip_atomic_load(bar, __ATOMIC_RELAXED, __HIP_MEMORY_SCOPE_AGENT) < step)
        __builtin_amdgcn_s_sleep(1);
      asm volatile("" ::: "memory");
    }
  }
  __syncthreads();
}

// NOTE: function, not macro — macro params named w/x collide with .w/.x members.
__device__ __forceinline__ void dot4(float& a, float4 wv, float4 xv) {
  a = fmaf(wv.x, xv.x, a);
  a = fmaf(wv.y, xv.y, a);
  a = fmaf(wv.z, xv.z, a);
  a = fmaf(wv.w, xv.w, a);
}

#define DECL_ACC                                                        \
  float acc00 = 0.f, acc01 = 0.f, acc02 = 0.f, acc03 = 0.f,             \
        acc10 = 0.f, acc11 = 0.f, acc12 = 0.f, acc13 = 0.f,             \
        acc20 = 0.f, acc21 = 0.f, acc22 = 0.f, acc23 = 0.f,             \
        acc30 = 0.f, acc31 = 0.f, acc32 = 0.f, acc33 = 0.f;

#define KSTEP(p0, p1, p2, p3, K4)                                       \
  {                                                                     \
    const float4 xv0 = *(const float4*)&xls[bq4][(K4)];                 \
    const float4 xv1 = *(const float4*)&xls[bq4 + 1][(K4)];             \
    const float4 xv2 = *(const float4*)&xls[bq4 + 2][(K4)];             \
    const float4 xv3 = *(const float4*)&xls[bq4 + 3][(K4)];             \
    float4 wv;                                                          \
    wv = *(const float4*)(p0);                                          \
    dot4(acc00, wv, xv0); dot4(acc01, wv, xv1);                         \
    dot4(acc02, wv, xv2); dot4(acc03, wv, xv3);                         \
    wv = *(const float4*)(p1);                                          \
    dot4(acc10, wv, xv0); dot4(acc11, wv, xv1);                         \
    dot4(acc12, wv, xv2); dot4(acc13, wv, xv3);                         \
    wv = *(const float4*)(p2);                                          \
    dot4(acc20, wv, xv0); dot4(acc21, wv, xv1);                         \
    dot4(acc22, wv, xv2); dot4(acc23, wv, xv3);                         \
    wv = *(const float4*)(p3);                                          \
    dot4(acc30, wv, xv0); dot4(acc31, wv, xv1);                         \
    dot4(acc32, wv, xv2); dot4(acc33, wv, xv3);                         \
  }

#define RED5(v)                \
  {                            \
    v += __shfl_xor(v, 1);     \
    v += __shfl_xor(v, 2);     \
    v += __shfl_xor(v, 4);     \
    v += __shfl_xor(v, 8);     \
    v += __shfl_xor(v, 16);    \
  }

#define REDUCE_ALL                                                     \
  {                                                                    \
    RED5(acc00) RED5(acc01) RED5(acc02) RED5(acc03)                    \
    RED5(acc10) RED5(acc11) RED5(acc12) RED5(acc13)                    \
    RED5(acc20) RED5(acc21) RED5(acc22) RED5(acc23)                    \
    RED5(acc30) RED5(acc31) RED5(acc32) RED5(acc33)                    \
  }

#define WRITE_GLS                                                                   \
  {                                                                                 \
    if (kc == 0) {                                                                  \
      gls[jq][0][bq4] = acc00; gls[jq][0][bq4 + 1] = acc01;                         \
      gls[jq][0][bq4 + 2] = acc02; gls[jq][0][bq4 + 3] = acc03;                     \
      gls[jq][1][bq4] = acc10; gls[jq][1][bq4 + 1] = acc11;                         \
      gls[jq][1][bq4 + 2] = acc12; gls[jq][1][bq4 + 3] = acc13;                     \
      gls[jq][2][bq4] = acc20; gls[jq][2][bq4 + 1] = acc21;                         \
      gls[jq][2][bq4 + 2] = acc22; gls[jq][2][bq4 + 3] = acc23;                     \
      gls[jq][3][bq4] = acc30; gls[jq][3][bq4 + 1] = acc31;                         \
      gls[jq][3][bq4 + 2] = acc32; gls[jq][3][bq4 + 3] = acc33;                     \
    }                                                                               \
  }

__global__ __launch_bounds__(512, 2) void dec_seq(
    const float* __restrict__ enc_h, const float* __restrict__ enc_c,
    const int* __restrict__ tgt, const float* __restrict__ emb,
    const float* __restrict__ wih0, const float* __restrict__ whh0,
    const float* __restrict__ bih0, const float* __restrict__ bhh0,
    const float* __restrict__ wih1, const float* __restrict__ whh1,
    const float* __restrict__ bih1, const float* __restrict__ bhh1,
    float* __restrict__ h0b, float* __restrict__ h1b,
    float* __restrict__ x1, float* __restrict__ out2,
    unsigned* bar) {
  __shared__ float xls[16][2052];   // [batch][k], padded rows (2052 % 32 == 4)
  __shared__ float gls[4][4][16];   // [gate][dj][b]

  const int tid = threadIdx.x;
  const int wgid = blockIdx.x;          // 0..255 -> 4 hidden units each
  const int kc = tid & 31;              // split-K lane
  const int combo = tid >> 5;           // 0..15
  const int jq = combo >> 2;            // gate 0..3 (i,f,g,o)
  const int bq4 = (combo & 3) * 4;      // batch quad
  const int w4 = wgid * 4;
  unsigned step = 0;                    // monotonic barrier generation

  const int j0 = jq * 1024 + w4;        // first of this thread's 4 gate rows
  const float* wih0r0 = wih0 + (size_t)(j0 + 0) * 2560;
  const float* wih0r1 = wih0 + (size_t)(j0 + 1) * 2560;
  const float* wih0r2 = wih0 + (size_t)(j0 + 2) * 2560;
  const float* wih0r3 = wih0 + (size_t)(j0 + 3) * 2560;
  const float* whh0r0 = whh0 + (size_t)(j0 + 0) * 1024;
  const float* whh0r1 = whh0 + (size_t)(j0 + 1) * 1024;
  const float* whh0r2 = whh0 + (size_t)(j0 + 2) * 1024;
  const float* whh0r3 = whh0 + (size_t)(j0 + 3) * 1024;
  const float* wih1r0 = wih1 + (size_t)(j0 + 0) * 1024;
  const float* wih1r1 = wih1 + (size_t)(j0 + 1) * 1024;
  const float* wih1r2 = wih1 + (size_t)(j0 + 2) * 1024;
  const float* wih1r3 = wih1 + (size_t)(j0 + 3) * 1024;
  const float* whh1r0 = whh1 + (size_t)(j0 + 0) * 1024;
  const float* whh1r1 = whh1 + (size_t)(j0 + 1) * 1024;
  const float* whh1r2 = whh1 + (size_t)(j0 + 2) * 1024;
  const float* whh1r3 = whh1 + (size_t)(j0 + 3) * 1024;

  // gate-thread persistent state (valid for tid < 64)
  const int gdj = tid >> 4;  // 0..3
  const int gb = tid & 15;   // batch
  float cpA0 = 0.f, cpA1 = 0.f, cpA2 = 0.f, cpA3 = 0.f;
  float cpB0 = 0.f, cpB1 = 0.f, cpB2 = 0.f, cpB3 = 0.f;
  float c0r = 0.f, c1r = 0.f;

  // ---------------- INIT: ctx projection + biases + h/c init ----------------
  // stage ctx[b][k] = enc_h[k>>9][b][k&511] into xls[b][0..2047]
#pragma unroll
  for (int c = 0; c < 16; ++c) {
    int f4 = tid + c * 512;
    int b = f4 >> 9, kq = f4 & 511;
    const float4 v = *(const float4*)(enc_h + (kq >> 7) * 8192 + b * 512 + (kq & 127) * 4);
    *(float4*)&xls[b][kq * 4] = v;
  }
  __syncthreads();
  {
    DECL_ACC
#pragma unroll 4
    for (int i = 0; i < 16; ++i) {
      const int k4 = i * 128 + kc * 4;
      KSTEP(wih0r0 + 512 + k4, wih0r1 + 512 + k4, wih0r2 + 512 + k4, wih0r3 + 512 + k4, k4)
    }
    REDUCE_ALL
    WRITE_GLS
  }
  __syncthreads();
  if (tid < 64) {
    const int jp = w4 + gdj;
    cpA0 = gls[0][gdj][gb] + bih0[jp] + bhh0[jp];
    cpA1 = gls[1][gdj][gb] + bih0[1024 + jp] + bhh0[1024 + jp];
    cpA2 = gls[2][gdj][gb] + bih0[2048 + jp] + bhh0[2048 + jp];
    cpA3 = gls[3][gdj][gb] + bih0[3072 + jp] + bhh0[3072 + jp];
    cpB0 = bih1[jp] + bhh1[jp];
    cpB1 = bih1[1024 + jp] + bhh1[1024 + jp];
    cpB2 = bih1[2048 + jp] + bhh1[2048 + jp];
    cpB3 = bih1[3072 + jp] + bhh1[3072 + jp];
    const int dir = jp >> 9, e = jp & 511;
    c0r = enc_c[dir * 8192 + gb * 512 + e];
    c1r = enc_c[(2 + dir) * 8192 + gb * 512 + e];
    st_cv(h0b + gb * 1024 + jp, enc_h[dir * 8192 + gb * 512 + e]);
    st_cv(h1b + gb * 1024 + jp, enc_h[(2 + dir) * 8192 + gb * 512 + e]);
  }
  gsync(++step, bar);

  // ---------------- LAYER 0: 128 steps, K = 512 (emb) + 1024 (h) ----------------
  int cur = 0;
  for (int t = 0; t < 128; ++t) {
#pragma unroll
    for (int c = 0; c < 4; ++c) {
      int f4 = tid + c * 512;
      int b = f4 >> 7, kq = f4 & 127;
      int tok = (t == 0) ? 1 : tgt[b * 128 + (t - 1)];
      const float4 v = *(const float4*)(emb + (size_t)tok * 512 + kq * 4);
      *(float4*)&xls[b][kq * 4] = v;
    }
    stage64k(h0b + cur * 16384, 512, tid, xls);
    __syncthreads();
    {
      DECL_ACC
#pragma unroll 4
      for (int i = 0; i < 4; ++i) {
        const int k4 = i * 128 + kc * 4;
        KSTEP(wih0r0 + k4, wih0r1 + k4, wih0r2 + k4, wih0r3 + k4, k4)
      }
#pragma unroll 4
      for (int i = 4; i < 12; ++i) {
        const int k4 = i * 128 + kc * 4;
        const int kh = k4 - 512;
        KSTEP(whh0r0 + kh, whh0r1 + kh, whh0r2 + kh, whh0r3 + kh, k4)
      }
      REDUCE_ALL
      WRITE_GLS
    }
    __syncthreads();
    if (tid < 64) {
      const int jp = w4 + gdj;
      float gi = gls[0][gdj][gb] + cpA0;
      float gf = gls[1][gdj][gb] + cpA1;
      float gg = gls[2][gdj][gb] + cpA2;
      float go = gls[3][gdj][gb] + cpA3;
      c0r = sigf(gf) * c0r + sigf(gi) * tanh_(gg);
      float h = sigf(go) * tanh_(c0r);
      st_cv(h0b + (cur ^ 1) * 16384 + gb * 1024 + jp, h);
      st_cv(x1 + t * 16384 + gb * 1024 + jp, h);
    }
    gsync(++step, bar);
    cur ^= 1;
  }

  // ---------------- LAYER 1: 128 steps, K = 1024 (x1) + 1024 (h) ----------------
  int cur2 = 0;
  for (int t = 0; t < 128; ++t) {
    stage64k(x1 + t * 16384, 0, tid, xls);
    stage64k(h1b + cur2 * 16384, 1024, tid, xls);
    __syncthreads();
    {
      DECL_ACC
#pragma unroll 4
      for (int i = 0; i < 8; ++i) {
        const int k4 = i * 128 + kc * 4;
        KSTEP(wih1r0 + k4, wih1r1 + k4, wih1r2 + k4, wih1r3 + k4, k4)
      }
#pragma unroll 4
      for (int i = 8; i < 16; ++i) {
        const int k4 = i * 128 + kc * 4;
        const int kh = k4 - 1024;
        KSTEP(whh1r0 + kh, whh1r1 + kh, whh1r2 + kh, whh1r3 + kh, k4)
      }
      REDUCE_ALL
      WRITE_GLS
    }
    __syncthreads();
    if (tid < 64) {
      const int jp = w4 + gdj;
      float gi = gls[0][gdj][gb] + cpB0;
      float gf = gls[1][gdj][gb] + cpB1;
      float gg = gls[2][gdj][gb] + cpB2;
      float go = gls[3][gdj][gb] + cpB3;
      c1r = sigf(gf) * c1r + sigf(gi) * tanh_(gg);
      float h = sigf(go) * tanh_(c1r);
      st_cv(h1b + (cur2 ^ 1) * 16384 + gb * 1024 + jp, h);
      out2[(t * 16 + gb) * 1024 + jp] = tanh_(h);  // consumed by next kernel
    }
    gsync(++step, bar);
    cur2 ^= 1;
  }
}

// logits[b][t][v] = sum_h out2[t*16+b][h] * fcw[v][h] + fcb[v]
__global__ __launch_bounds__(256, 2) void fc_gemm(
    const float* __restrict__ A, const float* __restrict__ Bw,
    const float* __restrict__ bias, float* __restrict__ C) {
  __shared__ float Asl[32][128];  // [k][m]
  __shared__ float Bsl[32][128];  // [k][n]
  const int tid = threadIdx.x;
  const int m0 = blockIdx.x * 128;  // 16 m-tiles (fast axis -> L2 reuse of Bw)
  const int n0 = blockIdx.y * 128;  // 250 n-tiles
  const int q = tid >> 6;
  const int tx = ((q & 1) << 3) + (tid & 7);
  const int ty = ((q >> 1) << 3) + ((tid >> 3) & 7);
  const int sm = tid >> 1;
  const int sh = (tid & 1) << 4;
  float acc[8][8] = {};
  const float* As = A + (size_t)(m0 + sm) * 1024 + sh;
  const float* Bs = Bw + (size_t)(n0 + sm) * 1024 + sh;

  for (int k0 = 0; k0 < 1024; k0 += 32) {
    float4 a0 = *(const float4*)(As + k0);
    float4 a1 = *(const float4*)(As + k0 + 4);
    float4 a2 = *(const float4*)(As + k0 + 8);
    float4 a3 = *(const float4*)(As + k0 + 12);
    float4 b0 = *(const float4*)(Bs + k0);
    float4 b1 = *(const float4*)(Bs + k0 + 4);
    float4 b2 = *(const float4*)(Bs + k0 + 8);
    float4 b3 = *(const float4*)(Bs + k0 + 12);
    float ta[16], tb[16];
    *(float4*)&ta[0] = a0; *(float4*)&ta[4] = a1; *(float4*)&ta[8] = a2; *(float4*)&ta[12] = a3;
    *(float4*)&tb[0] = b0; *(float4*)&tb[4] = b1; *(float4*)&tb[8] = b2; *(float4*)&tb[12] = b3;
#pragma unroll
    for (int u = 0; u < 16; ++u) {
      Asl[sh + u][sm] = ta[u];
      Bsl[sh + u][sm] = tb[u];
    }
    __syncthreads();
#pragma unroll 8
    for (int kk = 0; kk < 32; ++kk) {
      const float4 A0 = *(const float4*)&Asl[kk][ty * 8];
      const float4 A1 = *(const float4*)&Asl[kk][ty * 8 + 4];
      const float4 B0 = *(const float4*)&Bsl[kk][tx * 8];
      const float4 B1 = *(const float4*)&Bsl[kk][tx * 8 + 4];
      const float av[8] = {A0.x, A0.y, A0.z, A0.w, A1.x, A1.y, A1.z, A1.w};
      const float bv[8] = {B0.x, B0.y, B0.z, B0.w, B1.x, B1.y, B1.z, B1.w};
#pragma unroll
      for (int i = 0; i < 8; ++i)
#pragma unroll
        for (int j = 0; j < 8; ++j) acc[i][j] = fmaf(av[i], bv[j], acc[i][j]);
    }
    __syncthreads();
  }

  const float4 bb0 = *(const float4*)&bias[n0 + tx * 8];
  const float4 bb1 = *(const float4*)&bias[n0 + tx * 8 + 4];
  const float bv[8] = {bb0.x, bb0.y, bb0.z, bb0.w, bb1.x, bb1.y, bb1.z, bb1.w};
#pragma unroll
  for (int i = 0; i < 8; ++i) {
    const int m = m0 + ty * 8 + i;
    float* dst = C + ((size_t)(m & 15) * 128 + (m >> 4)) * 32000 + n0 + tx * 8;
    float4 o0, o1;
    o0.x = acc[i][0] + bv[0]; o0.y = acc[i][1] + bv[1];
    o0.z = acc[i][2] + bv[2]; o0.w = acc[i][3] + bv[3];
    o1.x = acc[i][4] + bv[4]; o1.y = acc[i][5] + bv[5];
    o1.z = acc[i][6] + bv[6]; o1.w = acc[i][7] + bv[7];
    *(float4*)dst = o0;
    *(float4*)(dst + 4) = o1;
  }
}

extern "C" void kernel_launch(void* const* d_in, const int* in_sizes, int n_in,
                              void* d_out, int out_size, void* d_ws, size_t ws_size,
                              hipStream_t stream) {
  const float* enc_h = (const float*)d_in[0];
  const float* enc_c = (const float*)d_in[1];
  const int* tgt = (const int*)d_in[2];
  const float* emb = (const float*)d_in[3];
  const float* wih0 = (const float*)d_in[4];
  const float* whh0 = (const float*)d_in[5];
  const float* bih0 = (const float*)d_in[6];
  const float* bhh0 = (const float*)d_in[7];
  const float* wih1 = (const float*)d_in[8];
  const float* whh1 = (const float*)d_in[9];
  const float* bih1 = (const float*)d_in[10];
  const float* bhh1 = (const float*)d_in[11];
  const float* fcw = (const float*)d_in[12];
  const float* fcb = (const float*)d_in[13];
  float* logits = (float*)d_out;

  unsigned* bar = (unsigned*)d_ws;                  // 32 KB barrier region
  float* wsf = (float*)((char*)d_ws + 32768);
  float* h0b = wsf;                   // 2 * 16384
  float* h1b = wsf + 32768;           // 2 * 16384
  float* x1 = wsf + 65536;            // 128 * 16384
  float* out2 = x1 + 2097152;         // 128 * 16384

  // zero generation word + 256 arrival flags (64B stride) each launch
  hipMemsetAsync(d_ws, 0, 64 + 256 * 64, stream);
  dec_seq<<<NBLK, 512, 0, stream>>>(enc_h, enc_c, tgt, emb, wih0, whh0, bih0, bhh0,
                                    wih1, whh1, bih1, bhh1, h0b, h1b, x1, out2, bar);
  fc_gemm<<<dim3(16, 250), 256, 0, stream>>>(out2, fcw, fcb, logits);
}

// Round 5
// 3486.093 us; speedup vs baseline: 5.2115x; 1.3449x over previous
//
#include <hip/hip_runtime.h>

// Decoder: B=16, T=128, V=32000, E=512, H=1024 (2 LSTM layers), CTX=2048.
// dec_seq: persistent kernel, 256 blocks x 512 threads, relaxed-poll barrier
//   (acquire-per-poll emits buffer_inv -> L2 flush storm; R4 fixed).
//   out2 now written as bf16 for the MFMA logits GEMM.
// fc_gemm_mfma: bf16 MFMA GEMM [2048x1024]x[32000x1024]^T -> [16][128][32000]
//   A (out2b) already bf16; B (fcw) converted fp32->bf16 on the fly.
//   128x128 tile, 4 waves, BK=32, LDS rows padded to 40 ushorts (2-way banks).

#define NBLK 256

typedef float f32x4 __attribute__((ext_vector_type(4)));
typedef __bf16 bf16x8 __attribute__((ext_vector_type(8)));
typedef unsigned short u16;

__device__ __forceinline__ float sigf(float x) { return 1.0f / (1.0f + __expf(-x)); }
__device__ __forceinline__ float tanh_(float x) {
  x = fminf(15.0f, fmaxf(-15.0f, x));
  float e = __expf(2.0f * x);
  return (e - 1.0f) / (e + 1.0f);
}

__device__ __forceinline__ u16 f2bf(float f) {
  __bf16 h = (__bf16)f;  // RNE, native on gfx950 (v_cvt_pk_bf16_f32 when paired)
  return __builtin_bit_cast(u16, h);
}

// Coherent (L2-bypass) scalar store: write-through to memory side.
__device__ __forceinline__ void st_cv(float* p, float v) {
  asm volatile("global_store_dword %0, %1, off sc0 sc1" :: "v"(p), "v"(v) : "memory");
}

// 8 coherent dwordx4 loads in flight, one waitcnt.
__device__ __forceinline__ void ld8_cv(const float* a0, const float* a1, const float* a2,
                                       const float* a3, const float* a4, const float* a5,
                                       const float* a6, const float* a7,
                                       f32x4& v0, f32x4& v1, f32x4& v2, f32x4& v3,
                                       f32x4& v4, f32x4& v5, f32x4& v6, f32x4& v7) {
  asm volatile(
      "global_load_dwordx4 %0, %8, off sc0 sc1\n\t"
      "global_load_dwordx4 %1, %9, off sc0 sc1\n\t"
      "global_load_dwordx4 %2, %10, off sc0 sc1\n\t"
      "global_load_dwordx4 %3, %11, off sc0 sc1\n\t"
      "global_load_dwordx4 %4, %12, off sc0 sc1\n\t"
      "global_load_dwordx4 %5, %13, off sc0 sc1\n\t"
      "global_load_dwordx4 %6, %14, off sc0 sc1\n\t"
      "global_load_dwordx4 %7, %15, off sc0 sc1\n\t"
      "s_waitcnt vmcnt(0)"
      : "=&v"(v0), "=&v"(v1), "=&v"(v2), "=&v"(v3),
        "=&v"(v4), "=&v"(v5), "=&v"(v6), "=&v"(v7)
      : "v"(a0), "v"(a1), "v"(a2), "v"(a3), "v"(a4), "v"(a5), "v"(a6), "v"(a7)
      : "memory");
}

// Stage a 16x1024 float slab (64KB) src -> xls[0..15][dstoff..dstoff+1023].
__device__ __forceinline__ void stage64k(const float* src, int dstoff, int tid,
                                         float xls[16][2052]) {
  f32x4 v0, v1, v2, v3, v4, v5, v6, v7;
  const float* s = src + 4 * tid;
  ld8_cv(s, s + 2048, s + 4096, s + 6144, s + 8192, s + 10240, s + 12288, s + 14336,
         v0, v1, v2, v3, v4, v5, v6, v7);
  const int bb = tid >> 8, k4 = (tid & 255) * 4;
  *(f32x4*)&xls[bb + 0][dstoff + k4] = v0;
  *(f32x4*)&xls[bb + 2][dstoff + k4] = v1;
  *(f32x4*)&xls[bb + 4][dstoff + k4] = v2;
  *(f32x4*)&xls[bb + 6][dstoff + k4] = v3;
  *(f32x4*)&xls[bb + 8][dstoff + k4] = v4;
  *(f32x4*)&xls[bb + 10][dstoff + k4] = v5;
  *(f32x4*)&xls[bb + 12][dstoff + k4] = v6;
  *(f32x4*)&xls[bb + 14][dstoff + k4] = v7;
}

// bar layout (uint32 idx): [0] = generation word; [16 + wgid*16] = per-block
// arrival flag (64B stride). Monotonic step counter, memset 0 per launch.
// All polls RELAXED (no buffer_inv); flag stores RELEASE.
__device__ __forceinline__ void gsync(unsigned step, unsigned* bar) {
  __syncthreads();
  const int tid = threadIdx.x;
  if (blockIdx.x == 0) {
    if (tid < 64) {
      if (tid == 0) {
        asm volatile("s_waitcnt vmcnt(0)" ::: "memory");
        __hip_atomic_store(bar + 16, step, __ATOMIC_RELEASE, __HIP_MEMORY_SCOPE_AGENT);
      }
      const int base = 16 + tid * 64;
      for (;;) {
        bool mine = true;
#pragma unroll
        for (int j = 0; j < 4; ++j)
          mine &= (__hip_atomic_load(bar + base + j * 16, __ATOMIC_RELAXED,
                                     __HIP_MEMORY_SCOPE_AGENT) >= step);
        if (__all(mine)) break;
        __builtin_amdgcn_s_sleep(1);
      }
      asm volatile("" ::: "memory");
      if (tid == 0)
        __hip_atomic_store(bar, step, __ATOMIC_RELEASE, __HIP_MEMORY_SCOPE_AGENT);
    }
  } else {
    if (tid == 0) {
      asm volatile("s_waitcnt vmcnt(0)" ::: "memory");
      __hip_atomic_store(bar + 16 + blockIdx.x * 16, step, __ATOMIC_RELEASE,
                         __HIP_MEMORY_SCOPE_AGENT);
      while (__hip_atomic_load(bar, __ATOMIC_RELAXED, __HIP_MEMORY_SCOPE_AGENT) < step)
        __builtin_amdgcn_s_sleep(1);
      asm volatile("" ::: "memory");
    }
  }
  __syncthreads();
}

__device__ __forceinline__ void dot4(float& a, float4 wv, float4 xv) {
  a = fmaf(wv.x, xv.x, a);
  a = fmaf(wv.y, xv.y, a);
  a = fmaf(wv.z, xv.z, a);
  a = fmaf(wv.w, xv.w, a);
}

#define DECL_ACC                                                        \
  float acc00 = 0.f, acc01 = 0.f, acc02 = 0.f, acc03 = 0.f,             \
        acc10 = 0.f, acc11 = 0.f, acc12 = 0.f, acc13 = 0.f,             \
        acc20 = 0.f, acc21 = 0.f, acc22 = 0.f, acc23 = 0.f,             \
        acc30 = 0.f, acc31 = 0.f, acc32 = 0.f, acc33 = 0.f;

#define KSTEP(p0, p1, p2, p3, K4)                                       \
  {                                                                     \
    const float4 xv0 = *(const float4*)&xls[bq4][(K4)];                 \
    const float4 xv1 = *(const float4*)&xls[bq4 + 1][(K4)];             \
    const float4 xv2 = *(const float4*)&xls[bq4 + 2][(K4)];             \
    const float4 xv3 = *(const float4*)&xls[bq4 + 3][(K4)];             \
    float4 wv;                                                          \
    wv = *(const float4*)(p0);                                          \
    dot4(acc00, wv, xv0); dot4(acc01, wv, xv1);                         \
    dot4(acc02, wv, xv2); dot4(acc03, wv, xv3);                         \
    wv = *(const float4*)(p1);                                          \
    dot4(acc10, wv, xv0); dot4(acc11, wv, xv1);                         \
    dot4(acc12, wv, xv2); dot4(acc13, wv, xv3);                         \
    wv = *(const float4*)(p2);                                          \
    dot4(acc20, wv, xv0); dot4(acc21, wv, xv1);                         \
    dot4(acc22, wv, xv2); dot4(acc23, wv, xv3);                         \
    wv = *(const float4*)(p3);                                          \
    dot4(acc30, wv, xv0); dot4(acc31, wv, xv1);                         \
    dot4(acc32, wv, xv2); dot4(acc33, wv, xv3);                         \
  }

#define RED5(v)                \
  {                            \
    v += __shfl_xor(v, 1);     \
    v += __shfl_xor(v, 2);     \
    v += __shfl_xor(v, 4);     \
    v += __shfl_xor(v, 8);     \
    v += __shfl_xor(v, 16);    \
  }

#define REDUCE_ALL                                                     \
  {                                                                    \
    RED5(acc00) RED5(acc01) RED5(acc02) RED5(acc03)                    \
    RED5(acc10) RED5(acc11) RED5(acc12) RED5(acc13)                    \
    RED5(acc20) RED5(acc21) RED5(acc22) RED5(acc23)                    \
    RED5(acc30) RED5(acc31) RED5(acc32) RED5(acc33)                    \
  }

#define WRITE_GLS                                                                   \
  {                                                                                 \
    if (kc == 0) {                                                                  \
      gls[jq][0][bq4] = acc00; gls[jq][0][bq4 + 1] = acc01;                         \
      gls[jq][0][bq4 + 2] = acc02; gls[jq][0][bq4 + 3] = acc03;                     \
      gls[jq][1][bq4] = acc10; gls[jq][1][bq4 + 1] = acc11;                         \
      gls[jq][1][bq4 + 2] = acc12; gls[jq][1][bq4 + 3] = acc13;                     \
      gls[jq][2][bq4] = acc20; gls[jq][2][bq4 + 1] = acc21;                         \
      gls[jq][2][bq4 + 2] = acc22; gls[jq][2][bq4 + 3] = acc23;                     \
      gls[jq][3][bq4] = acc30; gls[jq][3][bq4 + 1] = acc31;                         \
      gls[jq][3][bq4 + 2] = acc32; gls[jq][3][bq4 + 3] = acc33;                     \
    }                                                                               \
  }

__global__ __launch_bounds__(512, 2) void dec_seq(
    const float* __restrict__ enc_h, const float* __restrict__ enc_c,
    const int* __restrict__ tgt, const float* __restrict__ emb,
    const float* __restrict__ wih0, const float* __restrict__ whh0,
    const float* __restrict__ bih0, const float* __restrict__ bhh0,
    const float* __restrict__ wih1, const float* __restrict__ whh1,
    const float* __restrict__ bih1, const float* __restrict__ bhh1,
    float* __restrict__ h0b, float* __restrict__ h1b,
    float* __restrict__ x1, u16* __restrict__ out2b,
    unsigned* bar) {
  __shared__ float xls[16][2052];
  __shared__ float gls[4][4][16];

  const int tid = threadIdx.x;
  const int wgid = blockIdx.x;
  const int kc = tid & 31;
  const int combo = tid >> 5;
  const int jq = combo >> 2;
  const int bq4 = (combo & 3) * 4;
  const int w4 = wgid * 4;
  unsigned step = 0;

  const int j0 = jq * 1024 + w4;
  const float* wih0r0 = wih0 + (size_t)(j0 + 0) * 2560;
  const float* wih0r1 = wih0 + (size_t)(j0 + 1) * 2560;
  const float* wih0r2 = wih0 + (size_t)(j0 + 2) * 2560;
  const float* wih0r3 = wih0 + (size_t)(j0 + 3) * 2560;
  const float* whh0r0 = whh0 + (size_t)(j0 + 0) * 1024;
  const float* whh0r1 = whh0 + (size_t)(j0 + 1) * 1024;
  const float* whh0r2 = whh0 + (size_t)(j0 + 2) * 1024;
  const float* whh0r3 = whh0 + (size_t)(j0 + 3) * 1024;
  const float* wih1r0 = wih1 + (size_t)(j0 + 0) * 1024;
  const float* wih1r1 = wih1 + (size_t)(j0 + 1) * 1024;
  const float* wih1r2 = wih1 + (size_t)(j0 + 2) * 1024;
  const float* wih1r3 = wih1 + (size_t)(j0 + 3) * 1024;
  const float* whh1r0 = whh1 + (size_t)(j0 + 0) * 1024;
  const float* whh1r1 = whh1 + (size_t)(j0 + 1) * 1024;
  const float* whh1r2 = whh1 + (size_t)(j0 + 2) * 1024;
  const float* whh1r3 = whh1 + (size_t)(j0 + 3) * 1024;

  const int gdj = tid >> 4;
  const int gb = tid & 15;
  float cpA0 = 0.f, cpA1 = 0.f, cpA2 = 0.f, cpA3 = 0.f;
  float cpB0 = 0.f, cpB1 = 0.f, cpB2 = 0.f, cpB3 = 0.f;
  float c0r = 0.f, c1r = 0.f;

  // ---------------- INIT ----------------
#pragma unroll
  for (int c = 0; c < 16; ++c) {
    int f4 = tid + c * 512;
    int b = f4 >> 9, kq = f4 & 511;
    const float4 v = *(const float4*)(enc_h + (kq >> 7) * 8192 + b * 512 + (kq & 127) * 4);
    *(float4*)&xls[b][kq * 4] = v;
  }
  __syncthreads();
  {
    DECL_ACC
#pragma unroll 4
    for (int i = 0; i < 16; ++i) {
      const int k4 = i * 128 + kc * 4;
      KSTEP(wih0r0 + 512 + k4, wih0r1 + 512 + k4, wih0r2 + 512 + k4, wih0r3 + 512 + k4, k4)
    }
    REDUCE_ALL
    WRITE_GLS
  }
  __syncthreads();
  if (tid < 64) {
    const int jp = w4 + gdj;
    cpA0 = gls[0][gdj][gb] + bih0[jp] + bhh0[jp];
    cpA1 = gls[1][gdj][gb] + bih0[1024 + jp] + bhh0[1024 + jp];
    cpA2 = gls[2][gdj][gb] + bih0[2048 + jp] + bhh0[2048 + jp];
    cpA3 = gls[3][gdj][gb] + bih0[3072 + jp] + bhh0[3072 + jp];
    cpB0 = bih1[jp] + bhh1[jp];
    cpB1 = bih1[1024 + jp] + bhh1[1024 + jp];
    cpB2 = bih1[2048 + jp] + bhh1[2048 + jp];
    cpB3 = bih1[3072 + jp] + bhh1[3072 + jp];
    const int dir = jp >> 9, e = jp & 511;
    c0r = enc_c[dir * 8192 + gb * 512 + e];
    c1r = enc_c[(2 + dir) * 8192 + gb * 512 + e];
    st_cv(h0b + gb * 1024 + jp, enc_h[dir * 8192 + gb * 512 + e]);
    st_cv(h1b + gb * 1024 + jp, enc_h[(2 + dir) * 8192 + gb * 512 + e]);
  }
  gsync(++step, bar);

  // ---------------- LAYER 0 ----------------
  int cur = 0;
  for (int t = 0; t < 128; ++t) {
#pragma unroll
    for (int c = 0; c < 4; ++c) {
      int f4 = tid + c * 512;
      int b = f4 >> 7, kq = f4 & 127;
      int tok = (t == 0) ? 1 : tgt[b * 128 + (t - 1)];
      const float4 v = *(const float4*)(emb + (size_t)tok * 512 + kq * 4);
      *(float4*)&xls[b][kq * 4] = v;
    }
    stage64k(h0b + cur * 16384, 512, tid, xls);
    __syncthreads();
    {
      DECL_ACC
#pragma unroll 4
      for (int i = 0; i < 4; ++i) {
        const int k4 = i * 128 + kc * 4;
        KSTEP(wih0r0 + k4, wih0r1 + k4, wih0r2 + k4, wih0r3 + k4, k4)
      }
#pragma unroll 4
      for (int i = 4; i < 12; ++i) {
        const int k4 = i * 128 + kc * 4;
        const int kh = k4 - 512;
        KSTEP(whh0r0 + kh, whh0r1 + kh, whh0r2 + kh, whh0r3 + kh, k4)
      }
      REDUCE_ALL
      WRITE_GLS
    }
    __syncthreads();
    if (tid < 64) {
      const int jp = w4 + gdj;
      float gi = gls[0][gdj][gb] + cpA0;
      float gf = gls[1][gdj][gb] + cpA1;
      float gg = gls[2][gdj][gb] + cpA2;
      float go = gls[3][gdj][gb] + cpA3;
      c0r = sigf(gf) * c0r + sigf(gi) * tanh_(gg);
      float h = sigf(go) * tanh_(c0r);
      st_cv(h0b + (cur ^ 1) * 16384 + gb * 1024 + jp, h);
      st_cv(x1 + t * 16384 + gb * 1024 + jp, h);
    }
    gsync(++step, bar);
    cur ^= 1;
  }

  // ---------------- LAYER 1 ----------------
  int cur2 = 0;
  for (int t = 0; t < 128; ++t) {
    stage64k(x1 + t * 16384, 0, tid, xls);
    stage64k(h1b + cur2 * 16384, 1024, tid, xls);
    __syncthreads();
    {
      DECL_ACC
#pragma unroll 4
      for (int i = 0; i < 8; ++i) {
        const int k4 = i * 128 + kc * 4;
        KSTEP(wih1r0 + k4, wih1r1 + k4, wih1r2 + k4, wih1r3 + k4, k4)
      }
#pragma unroll 4
      for (int i = 8; i < 16; ++i) {
        const int k4 = i * 128 + kc * 4;
        const int kh = k4 - 1024;
        KSTEP(whh1r0 + kh, whh1r1 + kh, whh1r2 + kh, whh1r3 + kh, k4)
      }
      REDUCE_ALL
      WRITE_GLS
    }
    __syncthreads();
    if (tid < 64) {
      const int jp = w4 + gdj;
      float gi = gls[0][gdj][gb] + cpB0;
      float gf = gls[1][gdj][gb] + cpB1;
      float gg = gls[2][gdj][gb] + cpB2;
      float go = gls[3][gdj][gb] + cpB3;
      c1r = sigf(gf) * c1r + sigf(gi) * tanh_(gg);
      float h = sigf(go) * tanh_(c1r);
      st_cv(h1b + (cur2 ^ 1) * 16384 + gb * 1024 + jp, h);
      out2b[(t * 16 + gb) * 1024 + jp] = f2bf(tanh_(h));  // bf16 for MFMA GEMM
    }
    gsync(++step, bar);
    cur2 ^= 1;
  }
}

// logits[b][t][v] = sum_h out2[m=t*16+b][h] * fcw[v][h] + fcb[v]
// A bf16 [2048][1024]; B fp32 [32000][1024] (converted per tile); C fp32.
// 128x128 tile, 4 waves (2x2 of 64x64), mfma_f32_16x16x32_bf16, BK=32.
__global__ __launch_bounds__(256, 2) void fc_gemm_mfma(
    const u16* __restrict__ A, const float* __restrict__ Bw,
    const float* __restrict__ bias, float* __restrict__ C) {
  // rows padded to 40 ushorts (80B, 20 dwords): gcd(20,32)=4 -> 8 distinct
  // bank offsets across 16 rows -> 2-way conflict (free) on ds_read_b128.
  __shared__ __align__(16) u16 Al[128][40];
  __shared__ __align__(16) u16 Bl[128][40];

  const int tid = threadIdx.x;
  const int m0 = blockIdx.x * 128;  // 16 m-tiles (fast axis -> L2 reuse of B panel)
  const int n0 = blockIdx.y * 128;  // 250 n-tiles
  const int wave = tid >> 6;
  const int lane = tid & 63;
  const int wm = (wave & 1) * 64;
  const int wn = (wave >> 1) * 64;
  const int fr = lane & 15;   // frag M/N index
  const int ks = lane >> 4;   // frag K-slice (8 elems each)

  // staging: thread -> (row 0..127, half 0/1); 16 elems per thread per tile
  const int srow = tid >> 1;
  const int sh16 = (tid & 1) * 16;

  const u16* Ag = A + (size_t)(m0 + srow) * 1024 + sh16;
  const float* Bg = Bw + (size_t)(n0 + srow) * 1024 + sh16;

  f32x4 acc[4][4] = {};  // [mi][nj]

  for (int k0 = 0; k0 < 1024; k0 += 32) {
    // global loads first (overlap with barrier)
    uint4 a0 = *(const uint4*)(Ag + k0);
    uint4 a1 = *(const uint4*)(Ag + k0 + 8);
    float bfv[16];
    *(float4*)&bfv[0] = *(const float4*)(Bg + k0);
    *(float4*)&bfv[4] = *(const float4*)(Bg + k0 + 4);
    *(float4*)&bfv[8] = *(const float4*)(Bg + k0 + 8);
    *(float4*)&bfv[12] = *(const float4*)(Bg + k0 + 12);
    u16 bu[16];
#pragma unroll
    for (int u = 0; u < 16; ++u) bu[u] = f2bf(bfv[u]);

    __syncthreads();  // previous iteration's LDS reads done
    *(uint4*)&Al[srow][sh16] = a0;
    *(uint4*)&Al[srow][sh16 + 8] = a1;
    *(uint4*)&Bl[srow][sh16] = *(uint4*)&bu[0];
    *(uint4*)&Bl[srow][sh16 + 8] = *(uint4*)&bu[8];
    __syncthreads();

    bf16x8 af[4], bf[4];
#pragma unroll
    for (int i = 0; i < 4; ++i) af[i] = *(const bf16x8*)&Al[wm + i * 16 + fr][ks * 8];
#pragma unroll
    for (int j = 0; j < 4; ++j) bf[j] = *(const bf16x8*)&Bl[wn + j * 16 + fr][ks * 8];
#pragma unroll
    for (int i = 0; i < 4; ++i)
#pragma unroll
      for (int j = 0; j < 4; ++j)
        acc[i][j] = __builtin_amdgcn_mfma_f32_16x16x32_bf16(af[i], bf[j], acc[i][j], 0, 0, 0);
  }

  float bj[4];
#pragma unroll
  for (int j = 0; j < 4; ++j) bj[j] = bias[n0 + wn + j * 16 + fr];

  const int mrb = (lane >> 4) * 4;  // D row base within frag
#pragma unroll
  for (int i = 0; i < 4; ++i) {
#pragma unroll
    for (int r = 0; r < 4; ++r) {
      const int m = m0 + wm + i * 16 + mrb + r;
      float* dst = C + ((size_t)(m & 15) * 128 + (m >> 4)) * 32000;
#pragma unroll
      for (int j = 0; j < 4; ++j) {
        dst[n0 + wn + j * 16 + fr] = acc[i][j][r] + bj[j];
      }
    }
  }
}

extern "C" void kernel_launch(void* const* d_in, const int* in_sizes, int n_in,
                              void* d_out, int out_size, void* d_ws, size_t ws_size,
                              hipStream_t stream) {
  const float* enc_h = (const float*)d_in[0];
  const float* enc_c = (const float*)d_in[1];
  const int* tgt = (const int*)d_in[2];
  const float* emb = (const float*)d_in[3];
  const float* wih0 = (const float*)d_in[4];
  const float* whh0 = (const float*)d_in[5];
  const float* bih0 = (const float*)d_in[6];
  const float* bhh0 = (const float*)d_in[7];
  const float* wih1 = (const float*)d_in[8];
  const float* whh1 = (const float*)d_in[9];
  const float* bih1 = (const float*)d_in[10];
  const float* bhh1 = (const float*)d_in[11];
  const float* fcw = (const float*)d_in[12];
  const float* fcb = (const float*)d_in[13];
  float* logits = (float*)d_out;

  unsigned* bar = (unsigned*)d_ws;                  // 32 KB barrier region
  float* wsf = (float*)((char*)d_ws + 32768);
  float* h0b = wsf;                   // 2 * 16384 f
  float* h1b = wsf + 32768;           // 2 * 16384 f
  float* x1 = wsf + 65536;            // 128 * 16384 f (8 MB)
  u16* out2b = (u16*)(x1 + 2097152);  // 2048 * 1024 bf16 (4 MB)

  hipMemsetAsync(d_ws, 0, 64 + 256 * 64, stream);
  dec_seq<<<NBLK, 512, 0, stream>>>(enc_h, enc_c, tgt, emb, wih0, whh0, bih0, bhh0,
                                    wih1, whh1, bih1, bhh1, h0b, h1b, x1, out2b, bar);
  fc_gemm_mfma<<<dim3(16, 250), 256, 0, stream>>>(out2b, fcw, fcb, logits);
}